// Round 2
// baseline (406.762 us; speedup 1.0000x reference)
//
#include <hip/hip_runtime.h>
#include <stdint.h>

typedef int v4i  __attribute__((ext_vector_type(4)));
typedef int v16i __attribute__((ext_vector_type(16)));

static constexpr int MDIM = 8192;   // B * S
static constexpr int NDIM = 4096;   // D_OUT
static constexpr int KDIM = 4096;   // D_IN

static constexpr int QBLOCKS = (MDIM * KDIM / 16) / 256;  // 8192
static constexpr int WBLOCKS = (NDIM * KDIM / 16) / 256;  // 4096

// Async global->LDS, 16B per lane: HW writes lane i at (wave-uniform base) + i*16.
__device__ __forceinline__ void lds_load16(const void* gptr, void* lptr) {
    __builtin_amdgcn_global_load_lds(
        (const __attribute__((address_space(1))) void*)(uintptr_t)gptr,
        (__attribute__((address_space(3))) void*)(uint32_t)(uintptr_t)lptr,
        16, 0, 0);
}

__device__ __forceinline__ int q1(float f, float s) {
    return (int)fminf(fmaxf(__builtin_rintf(f / s), -128.0f), 127.0f);
}
__device__ __forceinline__ int pack4(int a, int b, int c, int d) {
    return (a & 0xff) | ((b & 0xff) << 8) | ((c & 0xff) << 16) | ((d & 0xff) << 24);
}

__global__ __launch_bounds__(256) void prep_k(const float4* __restrict__ x,
                                              int4* __restrict__ xq,
                                              const int4* __restrict__ w,
                                              int4* __restrict__ wq,
                                              const float* __restrict__ s_in) {
    const int b = blockIdx.x;
    if (b < QBLOCKS) {
        const int i = b * 256 + threadIdx.x;
        const float s = s_in[0];
        const float4 v0 = x[4 * i + 0];
        const float4 v1 = x[4 * i + 1];
        const float4 v2 = x[4 * i + 2];
        const float4 v3 = x[4 * i + 3];
        int4 o;
        o.x = pack4(q1(v0.x, s), q1(v0.y, s), q1(v0.z, s), q1(v0.w, s));
        o.y = pack4(q1(v1.x, s), q1(v1.y, s), q1(v1.z, s), q1(v1.w, s));
        o.z = pack4(q1(v2.x, s), q1(v2.y, s), q1(v2.z, s), q1(v2.w, s));
        o.w = pack4(q1(v3.x, s), q1(v3.y, s), q1(v3.z, s), q1(v3.w, s));
        xq[i] = o;
    } else {
        const int i = (b - QBLOCKS) * 256 + threadIdx.x;
        const int4 a = w[4 * i + 0];
        const int4 c = w[4 * i + 1];
        const int4 d = w[4 * i + 2];
        const int4 e = w[4 * i + 3];
        int4 o;
        o.x = pack4(a.x, a.y, a.z, a.w);
        o.y = pack4(c.x, c.y, c.z, c.w);
        o.z = pack4(d.x, d.y, d.z, d.w);
        o.w = pack4(e.x, e.y, e.z, e.w);
        wq[i] = o;
    }
}

// ============================================================================
// 256x256 tile, 4-span K-loop, 32x32x32 i8 MFMA, read/MFMA overlap.
//
// Span = (slot, ks) = one 64-B K-half of one double-buffer slot. Per span per
// wave: 12 ds_read_b128 (two k-steps j0/j1 of K=32), 16 MFMA (4m x 2n x 2j),
// 2 STAGEs (4 global_load_lds). All 12 reads issue up front; first MFMA batch
// gates on lgkmcnt(6) so j1's reads drain under j0's MFMAs; cross-wave drift
// within the span (only ONE barrier per span) overlaps reads with MFMA across
// the 2 waves/SIMD.
//
// Hazards (one barrier/span): WAR -- each span's STAGE targets the region read
// in the immediately previous span; readers drain lgkm before their barrier
// arrival, stage issues after. RAW -- uniform vmcnt(8) at each span end with
// 12 outstanding drains the oldest 4 = exactly the region read 3 spans later;
// every wave's vmcnt precedes its barrier, so cross-wave visibility holds.
// Stage schedule (iter i, tiles 2i=slot0 / 2i+1=slot1):
//   spanA(0,0): stage s1.k1 <- T(2i+1).k1     spanC(1,0): stage s0.k1 <- T(2i+2).k1
//   spanB(0,1): stage s0.k0 <- T(2i+2).k0     spanD(1,1): stage s1.k0 <- T(2i+3).k0
// Peel (last iter): only spanA stages; waits VM8/VM4/VM0/none.
//
// Fragments (i8 32x32x32): A row = lane&31, k = (lane>>5)*16 + e;  B mirrors
// over Bt rows. LDS 64-B rows, 16-B chunk c of row r at slot c ^ ((r>>1)&3)
// (consecutive-8-lane groups cover all 8 bank-quads -> conflict-free). k-step
// j uses global chunk j*2 + (lane>>5); aO1 = aO0 ^ 32 flips the j bit.
// C/D: col = lane&31, row = (reg&3) + 8*(reg>>2) + 4*(lane>>5)  [m74/m101].
// ============================================================================
__global__ __launch_bounds__(512, 2) void gemm_i8_k(const int8_t* __restrict__ A,
                                                    const int8_t* __restrict__ Bt,
                                                    float* __restrict__ C,
                                                    const float* __restrict__ w_scale,
                                                    const float* __restrict__ in_scale) {
    __shared__ int8_t lds[131072];

    const int tid  = threadIdx.x;
    const int lane = tid & 63;
    const int wave = tid >> 6;
    const int wr = wave >> 2;          // 0..1  (M half)
    const int wc = wave & 3;           // 0..3  (N quarter)
    const int lr = lane & 31;
    const int h  = lane >> 5;          // k-half within a 32-B k-step

    // XCD-aware swizzle: 512 wgs, 8 XCDs, each XCD gets an 8x8 tile chunk.
    const int bid = blockIdx.x;
    const int xcd = bid & 7;
    const int j   = bid >> 3;
    const int bm  = (xcd >> 1) * 8 + (j >> 3);   // 0..31
    const int bn  = (xcd & 1) * 8 + (j & 7);     // 0..15

    // Staging: row = tid>>2; LDS slot (tid&3) gets global chunk (tid&3)^((row>>1)&3).
    const int srow  = tid >> 2;
    const int sperm = ((tid & 3) ^ ((tid >> 3) & 3)) << 4;
    const int8_t* gA = A  + (size_t)(bm * 256 + srow) * KDIM + sperm;
    const int8_t* gB = Bt + (size_t)(bn * 256 + srow) * KDIM + sperm;
    const int ldsT = tid * 16;

#define STAGE(MATBASE, GSRC, slot, ks, kbyte)                                              \
    lds_load16(GSRC + (kbyte) + (ks) * 64,                                                 \
               lds + (MATBASE) + (slot) * 32768 + (ks) * 16384 + ldsT);                    \
    lds_load16(GSRC + (kbyte) + (ks) * 64 + 524288,                                        \
               lds + (MATBASE) + (slot) * 32768 + (ks) * 16384 + 8192 + ldsT);

    // Fragment base offsets (swizzle depends only on lr bits, bases are mult-of-32 rows).
    const int sw0 = ((h ^ ((lr >> 1) & 3)) << 4);
    const int aO0 = (wr * 128 + lr) * 64 + sw0;
    const int aO1 = aO0 ^ 32;                       // k-step j=1: chunk ^= 2
    const int bO0 = 65536 + (wc * 64 + lr) * 64 + sw0;
    const int bO1 = bO0 ^ 32;

    v16i acc[4][2] = {{}};
    v4i a0[4], a1[4], b0[2], b1[2];

#define RD(off) (*(const v4i*)(lds + (off)))
#define VM8 asm volatile("s_waitcnt vmcnt(8)" ::: "memory");
#define VM4 asm volatile("s_waitcnt vmcnt(4)" ::: "memory");
#define VM0 asm volatile("s_waitcnt vmcnt(0)" ::: "memory");

#define SPAN(slot, ks, STA, STB, VMW)                                                      \
    {                                                                                      \
        constexpr int RG = (slot) * 32768 + (ks) * 16384;                                  \
        a0[0] = RD(aO0 + RG + 0 * 2048);                                                   \
        a0[1] = RD(aO0 + RG + 1 * 2048);                                                   \
        a0[2] = RD(aO0 + RG + 2 * 2048);                                                   \
        a0[3] = RD(aO0 + RG + 3 * 2048);                                                   \
        b0[0] = RD(bO0 + RG + 0 * 2048);                                                   \
        b0[1] = RD(bO0 + RG + 1 * 2048);                                                   \
        __builtin_amdgcn_sched_barrier(0); /* pin j0 group first for lgkmcnt(6) */         \
        STA                                                                                \
        a1[0] = RD(aO1 + RG + 0 * 2048);                                                   \
        a1[1] = RD(aO1 + RG + 1 * 2048);                                                   \
        a1[2] = RD(aO1 + RG + 2 * 2048);                                                   \
        a1[3] = RD(aO1 + RG + 3 * 2048);                                                   \
        b1[0] = RD(bO1 + RG + 0 * 2048);                                                   \
        b1[1] = RD(bO1 + RG + 1 * 2048);                                                   \
        STB                                                                                \
        asm volatile("s_waitcnt lgkmcnt(6)" ::: "memory"); /* j0 ready, j1 in flight */    \
        __builtin_amdgcn_sched_barrier(0);                                                 \
        __builtin_amdgcn_s_setprio(1);                                                     \
        _Pragma("unroll")                                                                  \
        for (int mt = 0; mt < 4; ++mt)                                                     \
            _Pragma("unroll")                                                              \
            for (int nt = 0; nt < 2; ++nt)                                                 \
                acc[mt][nt] = __builtin_amdgcn_mfma_i32_32x32x32_i8(                       \
                    a0[mt], b0[nt], acc[mt][nt], 0, 0, 0);                                 \
        asm volatile("s_waitcnt lgkmcnt(0)" ::: "memory"); /* j1 drained under j0 MFMA */  \
        __builtin_amdgcn_sched_barrier(0);                                                 \
        _Pragma("unroll")                                                                  \
        for (int mt = 0; mt < 4; ++mt)                                                     \
            _Pragma("unroll")                                                              \
            for (int nt = 0; nt < 2; ++nt)                                                 \
                acc[mt][nt] = __builtin_amdgcn_mfma_i32_32x32x32_i8(                       \
                    a1[mt], b1[nt], acc[mt][nt], 0, 0, 0);                                 \
        __builtin_amdgcn_s_setprio(0);                                                     \
        VMW                                                                                \
        __builtin_amdgcn_s_barrier();                                                      \
    }

    // Prologue: tile0 both K-halves + tile1.k0 (12 loads/wave).
    STAGE(0, gA, 0, 0, 0) STAGE(65536, gB, 0, 0, 0)
    STAGE(0, gA, 0, 1, 0) STAGE(65536, gB, 0, 1, 0)
    STAGE(0, gA, 1, 0, 128) STAGE(65536, gB, 1, 0, 128)
    VM8                                  // tile0.k0 landed; rest in flight
    __builtin_amdgcn_s_barrier();

#pragma unroll 1
    for (int it = 0; it < 15; ++it) {
        const int kb = it * 256;
        SPAN(0, 0, STAGE(0, gA, 1, 1, kb + 128), STAGE(65536, gB, 1, 1, kb + 128), VM8)
        SPAN(0, 1, STAGE(0, gA, 0, 0, kb + 256), STAGE(65536, gB, 0, 0, kb + 256), VM8)
        SPAN(1, 0, STAGE(0, gA, 0, 1, kb + 256), STAGE(65536, gB, 0, 1, kb + 256), VM8)
        SPAN(1, 1, STAGE(0, gA, 1, 0, kb + 384), STAGE(65536, gB, 1, 0, kb + 384), VM8)
    }
    // Peel last iteration (tiles 30, 31): only tile31.k1 still to stage.
    SPAN(0, 0, STAGE(0, gA, 1, 1, 3968), STAGE(65536, gB, 1, 1, 3968), VM8)
    SPAN(0, 1, , , VM4)
    SPAN(1, 0, , , VM0)
    SPAN(1, 1, , , )

    // Epilogue: col = lane&31, row = (reg&3) + 8*(reg>>2) + 4*h.
    const float fs = w_scale[0] * in_scale[0];
    float* Cb = C + (size_t)(bm * 256 + wr * 128 + h * 4) * NDIM + bn * 256 + wc * 64 + lr;
#pragma unroll
    for (int mt = 0; mt < 4; ++mt)
#pragma unroll
        for (int nt = 0; nt < 2; ++nt)
#pragma unroll
            for (int r = 0; r < 16; ++r)
                Cb[(size_t)(mt * 32 + (r & 3) + 8 * (r >> 2)) * NDIM + nt * 32] =
                    (float)acc[mt][nt][r] * fs;

#undef STAGE
#undef RD
#undef SPAN
#undef VM8
#undef VM4
#undef VM0
}

extern "C" void kernel_launch(void* const* d_in, const int* in_sizes, int n_in,
                              void* d_out, int out_size, void* d_ws, size_t ws_size,
                              hipStream_t stream) {
    const float* x        = (const float*)d_in[0];
    const int*   w        = (const int*)d_in[1];
    const float* w_scale  = (const float*)d_in[2];
    const float* in_scale = (const float*)d_in[3];
    float* out = (float*)d_out;

    int8_t* xq = (int8_t*)d_ws;                       // 33,554,432 B
    int8_t* wq = xq + (size_t)MDIM * KDIM;            // 16,777,216 B (48 MB total)

    prep_k<<<QBLOCKS + WBLOCKS, 256, 0, stream>>>(
        (const float4*)x, (int4*)xq, (const int4*)w, (int4*)wq, in_scale);

    gemm_i8_k<<<512, 512, 0, stream>>>(xq, wq, out, w_scale, in_scale);
}

// Round 3
// 389.278 us; speedup vs baseline: 1.0449x; 1.0449x over previous
//
#include <hip/hip_runtime.h>
#include <stdint.h>

typedef int v4i __attribute__((ext_vector_type(4)));

static constexpr int MDIM = 8192;   // B * S
static constexpr int NDIM = 4096;   // D_OUT
static constexpr int KDIM = 4096;   // D_IN

static constexpr int QBLOCKS = (MDIM * KDIM / 16) / 256;  // 8192
static constexpr int WBLOCKS = (NDIM * KDIM / 16) / 256;  // 4096

// Async global->LDS, 16B per lane: HW writes lane i at (wave-uniform base) + i*16.
__device__ __forceinline__ void lds_load16(const void* gptr, void* lptr) {
    __builtin_amdgcn_global_load_lds(
        (const __attribute__((address_space(1))) void*)(uintptr_t)gptr,
        (__attribute__((address_space(3))) void*)(uint32_t)(uintptr_t)lptr,
        16, 0, 0);
}

__device__ __forceinline__ int q1(float f, float s) {
    return (int)fminf(fmaxf(__builtin_rintf(f / s), -128.0f), 127.0f);
}
__device__ __forceinline__ int pack4(int a, int b, int c, int d) {
    return (a & 0xff) | ((b & 0xff) << 8) | ((c & 0xff) << 16) | ((d & 0xff) << 24);
}

__global__ __launch_bounds__(256) void prep_k(const float4* __restrict__ x,
                                              int4* __restrict__ xq,
                                              const int4* __restrict__ w,
                                              int4* __restrict__ wq,
                                              const float* __restrict__ s_in) {
    const int b = blockIdx.x;
    if (b < QBLOCKS) {
        const int i = b * 256 + threadIdx.x;
        const float s = s_in[0];
        const float4 v0 = x[4 * i + 0];
        const float4 v1 = x[4 * i + 1];
        const float4 v2 = x[4 * i + 2];
        const float4 v3 = x[4 * i + 3];
        int4 o;
        o.x = pack4(q1(v0.x, s), q1(v0.y, s), q1(v0.z, s), q1(v0.w, s));
        o.y = pack4(q1(v1.x, s), q1(v1.y, s), q1(v1.z, s), q1(v1.w, s));
        o.z = pack4(q1(v2.x, s), q1(v2.y, s), q1(v2.z, s), q1(v2.w, s));
        o.w = pack4(q1(v3.x, s), q1(v3.y, s), q1(v3.z, s), q1(v3.w, s));
        xq[i] = o;
    } else {
        const int i = (b - QBLOCKS) * 256 + threadIdx.x;
        const int4 a = w[4 * i + 0];
        const int4 c = w[4 * i + 1];
        const int4 d = w[4 * i + 2];
        const int4 e = w[4 * i + 3];
        int4 o;
        o.x = pack4(a.x, a.y, a.z, a.w);
        o.y = pack4(c.x, c.y, c.z, c.w);
        o.z = pack4(d.x, d.y, d.z, d.w);
        o.w = pack4(e.x, e.y, e.z, e.w);
        wq[i] = o;
    }
}

// ============================================================================
// 256x256 tile, 8-phase, ONE barrier/phase, fragment-pipelined int8 GEMM.
// Identical LDS layout / read / write / swizzle patterns to the verified
// round-1 kernel (0 bank conflicts); only the schedule changes:
//
//  * A-fragments double-buffered: phase p prefetches av for phase p+1 into
//    av[(p+1)&1]; MFMA p gates on lgkmcnt(4) (= exactly the prefetch left in
//    flight), so phase p's reads drained during phase p-1's MFMA window.
//  * bv (4 reads) issued in-phase on mh0 phases, held across the mh1 phase.
//  * One s_barrier per phase. Safe because (a) the lgkm gate drains every
//    read of >=1-phase-old regions before that wave's barrier; (b) all
//    in-flight reads at a barrier target region(p+1), disjoint from phase
//    p+1's stage target (verified for all 8 phases).
//  * Uniform vmcnt(6) at each phase end: stages are 2/phase, so VM6 retires
//    the stage issued 3 phases ago; every region's first read-issue is >= 4
//    phases after its stage (all four regions land exactly at 4).
//    Peel iteration drains VM6 -> VM4 -> VM2 -> VM0 (counts re-derived for
//    the missing stages).
// Stage schedule per iter i (tiles 2i=slot0, 2i+1=slot1), same as round 1:
//   P0/P1: s1.k1 (A,B) of tile 2i+1    P4/P5: s0.k1 (A,B) of tile 2i+2
//   P2/P3: s0.k0 (A,B) of tile 2i+2    P6/P7: s1.k0 (A,B) of tile 2i+3
// ============================================================================
__global__ __launch_bounds__(512, 2) void gemm_i8_k(const int8_t* __restrict__ A,
                                                    const int8_t* __restrict__ Bt,
                                                    float* __restrict__ C,
                                                    const float* __restrict__ w_scale,
                                                    const float* __restrict__ in_scale) {
    __shared__ int8_t lds[131072];

    const int tid  = threadIdx.x;
    const int lane = tid & 63;
    const int wave = tid >> 6;
    const int wr = wave >> 2;          // 0..1  (M half)
    const int wc = wave & 3;           // 0..3  (N quarter)
    const int lm = lane & 15;
    const int q  = lane >> 4;          // 16-B chunk within 64-B K-half

    // XCD-aware swizzle: 512 wgs, 8 XCDs, each XCD gets an 8x8 tile chunk.
    const int bid = blockIdx.x;
    const int xcd = bid & 7;
    const int j   = bid >> 3;
    const int bm  = (xcd >> 1) * 8 + (j >> 3);   // 0..31
    const int bn  = (xcd & 1) * 8 + (j & 7);     // 0..15

    // Staging: row = tid>>2; LDS slot (tid&3) gets global chunk (tid&3)^((row>>1)&3).
    const int srow  = tid >> 2;
    const int sperm = ((tid & 3) ^ ((tid >> 3) & 3)) << 4;
    const int8_t* gA = A  + (size_t)(bm * 256 + srow) * KDIM + sperm;
    const int8_t* gB = Bt + (size_t)(bn * 256 + srow) * KDIM + sperm;
    const int ldsT = tid * 16;

#define STAGE(MATBASE, GSRC, slot, ks, kbyte)                                              \
    lds_load16(GSRC + (kbyte) + (ks) * 64,                                                 \
               lds + (MATBASE) + (slot) * 32768 + (ks) * 16384 + ldsT);                    \
    lds_load16(GSRC + (kbyte) + (ks) * 64 + 524288,                                        \
               lds + (MATBASE) + (slot) * 32768 + (ks) * 16384 + 8192 + ldsT);

    // Fragment bases. row = wr*128 + mh*64 + mt*16 + lm; (row>>1)&3 == (lm>>1)&3.
    const int fsw = ((q ^ ((lm >> 1) & 3)) << 4);
    const int aB = (wr * 128 + lm) * 64 + fsw;
    const int bB = 65536 + (wc * 64 + lm) * 64 + fsw;

    v4i acc[8][4] = {{}};
    v4i av[2][4], bv[4];

#define RD(off) (*(const v4i*)(lds + (off)))
#define RGN(slot, ks) ((slot) * 32768 + (ks) * 16384)

#define PREF_AV(nb, slot, ks, mh)                                                          \
    av[nb][0] = RD(aB + RGN(slot, ks) + (mh) * 4096 + 0);                                  \
    av[nb][1] = RD(aB + RGN(slot, ks) + (mh) * 4096 + 1024);                               \
    av[nb][2] = RD(aB + RGN(slot, ks) + (mh) * 4096 + 2048);                               \
    av[nb][3] = RD(aB + RGN(slot, ks) + (mh) * 4096 + 3072);

#define READ_BV(slot, ks)                                                                  \
    bv[0] = RD(bB + RGN(slot, ks) + 0);                                                    \
    bv[1] = RD(bB + RGN(slot, ks) + 1024);                                                 \
    bv[2] = RD(bB + RGN(slot, ks) + 2048);                                                 \
    bv[3] = RD(bB + RGN(slot, ks) + 3072);

#define VM6 asm volatile("s_waitcnt vmcnt(6)" ::: "memory");
#define VM4 asm volatile("s_waitcnt vmcnt(4)" ::: "memory");
#define VM2 asm volatile("s_waitcnt vmcnt(2)" ::: "memory");
#define VM0 asm volatile("s_waitcnt vmcnt(0)" ::: "memory");

// BVR: READ_BV or empty. PRF: PREF_AV for phase p+1 or empty. STG: STAGE or
// empty. GATEN: lgkm count (4 = prefetch left in flight; 0 on final phase).
#define PHASE(mh, cb, BVR, PRF, STG, GATEN, VMW)                                           \
    {                                                                                      \
        BVR                                                                                \
        PRF                                                                                \
        STG                                                                                \
        asm volatile("s_waitcnt lgkmcnt(" #GATEN ")" ::: "memory");                        \
        __builtin_amdgcn_sched_barrier(0);                                                 \
        __builtin_amdgcn_s_setprio(1);                                                     \
        _Pragma("unroll")                                                                  \
        for (int mt = 0; mt < 4; ++mt)                                                     \
            _Pragma("unroll")                                                              \
            for (int nt = 0; nt < 4; ++nt)                                                 \
                acc[(mh) * 4 + mt][nt] = __builtin_amdgcn_mfma_i32_16x16x64_i8(            \
                    av[cb][mt], bv[nt], acc[(mh) * 4 + mt][nt], 0, 0, 0);                  \
        __builtin_amdgcn_s_setprio(0);                                                     \
        __builtin_amdgcn_sched_barrier(0);                                                 \
        VMW                                                                                \
        __builtin_amdgcn_s_barrier();                                                      \
    }

    // Prologue: tile0 both K-halves + tile1.k0 (12 loads/wave).
    STAGE(0, gA, 0, 0, 0) STAGE(65536, gB, 0, 0, 0)
    STAGE(0, gA, 0, 1, 0) STAGE(65536, gB, 0, 1, 0)
    STAGE(0, gA, 1, 0, 128) STAGE(65536, gB, 1, 0, 128)
    asm volatile("s_waitcnt vmcnt(8)" ::: "memory");   // tile0.k0 landed
    __builtin_amdgcn_s_barrier();
    PREF_AV(0, 0, 0, 0)                                // P0 fragments in flight

#pragma unroll 1
    for (int it = 0; it < 15; ++it) {
        const int kb = it * 256;
        PHASE(0, 0, READ_BV(0, 0), PREF_AV(1, 0, 0, 1), STAGE(0, gA, 1, 1, kb + 128), 4, VM6)
        PHASE(1, 1, ,               PREF_AV(0, 0, 1, 0), STAGE(65536, gB, 1, 1, kb + 128), 4, VM6)
        PHASE(0, 0, READ_BV(0, 1), PREF_AV(1, 0, 1, 1), STAGE(0, gA, 0, 0, kb + 256), 4, VM6)
        PHASE(1, 1, ,               PREF_AV(0, 1, 0, 0), STAGE(65536, gB, 0, 0, kb + 256), 4, VM6)
        PHASE(0, 0, READ_BV(1, 0), PREF_AV(1, 1, 0, 1), STAGE(0, gA, 0, 1, kb + 256), 4, VM6)
        PHASE(1, 1, ,               PREF_AV(0, 1, 1, 0), STAGE(65536, gB, 0, 1, kb + 256), 4, VM6)
        PHASE(0, 0, READ_BV(1, 1), PREF_AV(1, 1, 1, 1), STAGE(0, gA, 1, 0, kb + 384), 4, VM6)
        PHASE(1, 1, ,               PREF_AV(0, 0, 0, 0), STAGE(65536, gB, 1, 0, kb + 384), 4, VM6)
    }
    // Peeled last iteration (tiles 30, 31): only tile31.k1 still to stage.
    PHASE(0, 0, READ_BV(0, 0), PREF_AV(1, 0, 0, 1), STAGE(0, gA, 1, 1, 3968), 4, VM6)
    PHASE(1, 1, ,               PREF_AV(0, 0, 1, 0), STAGE(65536, gB, 1, 1, 3968), 4, VM6)
    PHASE(0, 0, READ_BV(0, 1), PREF_AV(1, 0, 1, 1), , 4, VM4)
    PHASE(1, 1, ,               PREF_AV(0, 1, 0, 0), , 4, VM2)
    PHASE(0, 0, READ_BV(1, 0), PREF_AV(1, 1, 0, 1), , 4, VM0)
    PHASE(1, 1, ,               PREF_AV(0, 1, 1, 0), , 4, )
    PHASE(0, 0, READ_BV(1, 1), PREF_AV(1, 1, 1, 1), , 4, )
    PHASE(1, 1, ,               ,                    , 0, )

    // Epilogue: D layout col = lane&15 (n), row = (lane>>4)*4 + reg (m).
    const float fs = w_scale[0] * in_scale[0];
    const int crow = q * 4;
#pragma unroll
    for (int m = 0; m < 8; ++m) {
#pragma unroll
        for (int n = 0; n < 4; ++n) {
            const size_t nn = (size_t)bn * 256 + wc * 64 + n * 16 + lm;
            const size_t mb = (size_t)bm * 256 + wr * 128 + m * 16 + crow;
#pragma unroll
            for (int r = 0; r < 4; ++r)
                C[(mb + r) * NDIM + nn] = (float)acc[m][n][r] * fs;
        }
    }

#undef STAGE
#undef RD
#undef RGN
#undef PREF_AV
#undef READ_BV
#undef PHASE
#undef VM6
#undef VM4
#undef VM2
#undef VM0
}

extern "C" void kernel_launch(void* const* d_in, const int* in_sizes, int n_in,
                              void* d_out, int out_size, void* d_ws, size_t ws_size,
                              hipStream_t stream) {
    const float* x        = (const float*)d_in[0];
    const int*   w        = (const int*)d_in[1];
    const float* w_scale  = (const float*)d_in[2];
    const float* in_scale = (const float*)d_in[3];
    float* out = (float*)d_out;

    int8_t* xq = (int8_t*)d_ws;                       // 33,554,432 B
    int8_t* wq = xq + (size_t)MDIM * KDIM;            // 16,777,216 B (48 MB total)

    prep_k<<<QBLOCKS + WBLOCKS, 256, 0, stream>>>(
        (const float4*)x, (int4*)xq, (const int4*)w, (int4*)wq, in_scale);

    dim3 grid(512);
    gemm_i8_k<<<grid, 512, 0, stream>>>(xq, wq, out, w_scale, in_scale);
}